// Round 1
// baseline (297.030 us; speedup 1.0000x reference)
//
#include <hip/hip_runtime.h>
#include <cstdint>

#define F 64
#define TILE1 8192     // edges per bucketing tile
#define MAXFB 1024     // max fine buckets (supports N <= 131072)
#define SCAN_BLK 1024

typedef short bf16x8 __attribute__((ext_vector_type(8)));
typedef float f32x4  __attribute__((ext_vector_type(4)));

// ---------------------------------------------------------------------------
// bf16 helpers
// ---------------------------------------------------------------------------
__device__ __forceinline__ unsigned short f2b(float f) {     // RNE round
    unsigned u = __float_as_uint(f);
    unsigned r = u + 0x7fffu + ((u >> 16) & 1u);
    return (unsigned short)(r >> 16);
}
__device__ __forceinline__ void add8(float* a, uint4 u) {
    const unsigned* p = (const unsigned*)&u;
#pragma unroll
    for (int i = 0; i < 4; ++i) {
        a[2 * i + 0] += __uint_as_float(p[i] << 16);
        a[2 * i + 1] += __uint_as_float(p[i] & 0xffff0000u);
    }
}

// ---------------------------------------------------------------------------
// Hist: per-tile histogram by fine bucket (dst >> 7), 782 bins in LDS.
// ---------------------------------------------------------------------------
__global__ __launch_bounds__(256) void hist_kernel(
    const int* __restrict__ dst, int* __restrict__ binMat,
    int E, int NB1, int nf) {
    __shared__ int h[MAXFB];
    int t = threadIdx.x;
    for (int i = t; i < nf; i += 256) h[i] = 0;
    __syncthreads();
    int base = blockIdx.x * TILE1;
    int end = min(base + TILE1, E);
    const int4* d4 = (const int4*)dst;
    int n4 = (end - base) >> 2;
    int b4 = base >> 2;
    for (int k = t; k < n4; k += 256) {
        int4 v = d4[b4 + k];
        atomicAdd(&h[v.x >> 7], 1);
        atomicAdd(&h[v.y >> 7], 1);
        atomicAdd(&h[v.z >> 7], 1);
        atomicAdd(&h[v.w >> 7], 1);
    }
    __syncthreads();
    for (int i = t; i < nf; i += 256) binMat[i * NB1 + blockIdx.x] = h[i];
}

// ---------------------------------------------------------------------------
// Multi-block exclusive scan (in-place) of binMat[len]
// ---------------------------------------------------------------------------
__global__ __launch_bounds__(SCAN_BLK) void scan_blocks_kernel(
    int* __restrict__ a, int* __restrict__ blockSums, int len) {
    __shared__ int sh[SCAN_BLK];
    int t = threadIdx.x;
    int i = blockIdx.x * SCAN_BLK + t;
    int v = (i < len) ? a[i] : 0;
    sh[t] = v;
    __syncthreads();
    for (int off = 1; off < SCAN_BLK; off <<= 1) {
        int add = (t >= off) ? sh[t - off] : 0;
        __syncthreads();
        sh[t] += add;
        __syncthreads();
    }
    int incl = sh[t];
    if (i < len) a[i] = incl - v;
    if (t == SCAN_BLK - 1) blockSums[blockIdx.x] = incl;
}

__global__ __launch_bounds__(SCAN_BLK) void scan_sums_kernel(
    int* __restrict__ blockSums, int nb) {
    __shared__ int sh[SCAN_BLK];
    int t = threadIdx.x;
    int v = (t < nb) ? blockSums[t] : 0;
    sh[t] = v;
    __syncthreads();
    for (int off = 1; off < SCAN_BLK; off <<= 1) {
        int add = (t >= off) ? sh[t - off] : 0;
        __syncthreads();
        sh[t] += add;
        __syncthreads();
    }
    if (t < nb) blockSums[t] = sh[t] - v;
}

__global__ __launch_bounds__(256) void scan_add_kernel(
    int* __restrict__ a, const int* __restrict__ blockSums, int len) {
    int i = blockIdx.x * 256 + threadIdx.x;
    if (i < len) a[i] += blockSums[i >> 10];
}

// ---------------------------------------------------------------------------
// Scatter: deterministic placement into fine-bucket-sorted stage2.
// Packed word: (dst & 127) << 17 | src   (needs N <= 131072)
// ---------------------------------------------------------------------------
__global__ __launch_bounds__(256) void scatter_kernel(
    const int* __restrict__ src, const int* __restrict__ dst,
    const int* __restrict__ binMat, unsigned* __restrict__ stage2,
    int E, int NB1, int nf) {
    __shared__ int cur[MAXFB];
    int t = threadIdx.x;
    for (int i = t; i < nf; i += 256) cur[i] = binMat[i * NB1 + blockIdx.x];
    __syncthreads();
    int base = blockIdx.x * TILE1;
    int end = min(base + TILE1, E);
    const int4* s4 = (const int4*)src;
    const int4* d4 = (const int4*)dst;
    int n4 = (end - base) >> 2;
    int b4 = base >> 2;
    for (int k = t; k < n4; k += 256) {
        int4 s = s4[b4 + k];
        int4 d = d4[b4 + k];
        int p0 = atomicAdd(&cur[d.x >> 7], 1);
        int p1 = atomicAdd(&cur[d.y >> 7], 1);
        int p2 = atomicAdd(&cur[d.z >> 7], 1);
        int p3 = atomicAdd(&cur[d.w >> 7], 1);
        stage2[p0] = ((unsigned)(d.x & 127) << 17) | (unsigned)s.x;
        stage2[p1] = ((unsigned)(d.y & 127) << 17) | (unsigned)s.y;
        stage2[p2] = ((unsigned)(d.z & 127) << 17) | (unsigned)s.z;
        stage2[p3] = ((unsigned)(d.w & 127) << 17) | (unsigned)s.w;
    }
}

// ---------------------------------------------------------------------------
// Phase 2: one block per fine bucket (128 nodes) -> csrSrc + rowStart.
// ---------------------------------------------------------------------------
__global__ __launch_bounds__(256) void phase2_kernel(
    const unsigned* __restrict__ stage2, const int* __restrict__ binMat,
    int* __restrict__ csrSrc, int* __restrict__ rowStart,
    int E, int NB1, int nf) {
    __shared__ int cnt[128];
    __shared__ int pre[129];
    __shared__ int cur[128];
    int b = blockIdx.x;
    int t = threadIdx.x;
    int s = binMat[b * NB1];
    int e2 = (b + 1 < nf) ? binMat[(b + 1) * NB1] : E;
    if (t < 128) cnt[t] = 0;
    __syncthreads();
    for (int i = s + t; i < e2; i += 256)
        atomicAdd(&cnt[(stage2[i] >> 17) & 127], 1);
    __syncthreads();
    if (t < 128) pre[t + 1] = cnt[t];
    if (t == 0) pre[0] = 0;
    __syncthreads();
    for (int off = 1; off < 128; off <<= 1) {
        int v = 0;
        if (t < 128 && (t + 1) > off) v = pre[t + 1 - off];
        __syncthreads();
        if (t < 128 && (t + 1) > off) pre[t + 1] += v;
        __syncthreads();
    }
    if (t < 128) cur[t] = pre[t];
    if (t < 129) rowStart[b * 128 + t] = s + pre[t];
    __syncthreads();
    for (int i = s + t; i < e2; i += 256) {
        unsigned w = stage2[i];
        int pos = atomicAdd(&cur[(w >> 17) & 127], 1);
        csrSrc[s + pos] = (int)(w & 0x1FFFFu);
    }
}

// ---------------------------------------------------------------------------
// Prep: weight B-fragments (blocks 0..11) + x -> bf16 (remaining blocks).
// ---------------------------------------------------------------------------
__global__ __launch_bounds__(256) void prep_kernel(
    const float* __restrict__ Wl0, const float* __restrict__ Wr0,
    const float* __restrict__ Wl1, const float* __restrict__ Wr1,
    const float* __restrict__ Wl2, const float* __restrict__ Wr2,
    ushort* __restrict__ wbuf,
    const float* __restrict__ x, ushort* __restrict__ xb, int nElem) {
    int b = blockIdx.x;
    int t = threadIdx.x;
    if (b < 12) {
        int g = b * 256 + t;          // g < 3072 = 3 sets * 16 frags * 64 lanes
        int set = g >> 10;
        int fl = g & 1023;
        int f = fl >> 6;              // frag id = s*4+ot
        int l = fl & 63;
        int s = f >> 2;
        int ot = f & 3;
        const float* Wl = (set == 0) ? Wl0 : (set == 1) ? Wl1 : Wl2;
        const float* Wr = (set == 0) ? Wr0 : (set == 1) ? Wr1 : Wr2;
        int o = ot * 16 + (l & 15);
        int k0 = s * 32 + (l >> 4) * 8;
        unsigned d[4];
#pragma unroll
        for (int p = 0; p < 4; ++p) {
            int ka = k0 + 2 * p, kb = k0 + 2 * p + 1;
            float va = (ka < 64) ? Wl[o * 64 + ka] : Wr[o * 64 + (ka - 64)];
            float vb = (kb < 64) ? Wl[o * 64 + kb] : Wr[o * 64 + (kb - 64)];
            d[p] = (unsigned)f2b(va) | ((unsigned)f2b(vb) << 16);
        }
        ((uint4*)wbuf)[g] = make_uint4(d[0], d[1], d[2], d[3]);
    } else {
        int i = (b - 12) * 256 + t;   // float4 index
        int n4 = nElem >> 2;
        if (i < n4) {
            float4 v = ((const float4*)x)[i];
            uint2 o;
            o.x = (unsigned)f2b(v.x) | ((unsigned)f2b(v.y) << 16);
            o.y = (unsigned)f2b(v.z) | ((unsigned)f2b(v.w) << 16);
            ((uint2*)xb)[i] = o;
        }
    }
}

// ---------------------------------------------------------------------------
// Fused layer: gather (register accumulate, 8 lanes/node, 4 nodes/thread)
//   -> LDS bf16 tile [128][72-stride] -> MFMA matvec -> transposed store.
// LDS buffer (18.4 KB) is reused for the output transpose (two 64-row halves)
// so 4 blocks/CU fit. flags: bit0 = tanh, bit1 = bf16 output.
// ---------------------------------------------------------------------------
__global__ __launch_bounds__(256, 4) void fused_layer(
    const ushort* __restrict__ hb, const int* __restrict__ rowStart,
    const int* __restrict__ csrSrc, const ushort* __restrict__ wbuf,
    const float* __restrict__ bl, void* __restrict__ out, int n, int flags) {
    // aggL: 128 rows x 72 ushorts (stride 144B: 16B-aligned b128, bank-spread)
    // reused after barrier as outT: 64 rows x 68 floats (17.4 KB <= 18.4 KB)
    __shared__ __align__(16) ushort smem[128 * 72];

    int t = threadIdx.x;
    int node0b = blockIdx.x * 128;
    const uint4* h16 = (const uint4*)hb;

    // ---- Phase A: gather into LDS ----
    {
        int c = t & 7;                 // 16B feature chunk
        int nlb = t >> 3;              // 0..31
#pragma unroll 1
        for (int r = 0; r < 4; ++r) {
            int nl = r * 32 + nlb;     // local node 0..127
            int node = node0b + nl;
            float a[8] = {0.f, 0.f, 0.f, 0.f, 0.f, 0.f, 0.f, 0.f};
            int e = rowStart[node];
            int end = rowStart[node + 1];
            for (; e + 3 < end; e += 4) {
                int s0 = csrSrc[e + 0];
                int s1 = csrSrc[e + 1];
                int s2 = csrSrc[e + 2];
                int s3 = csrSrc[e + 3];
                uint4 u0 = h16[(size_t)s0 * 8 + c];
                uint4 u1 = h16[(size_t)s1 * 8 + c];
                uint4 u2 = h16[(size_t)s2 * 8 + c];
                uint4 u3 = h16[(size_t)s3 * 8 + c];
                add8(a, u0); add8(a, u1); add8(a, u2); add8(a, u3);
            }
            for (; e < end; ++e) {
                uint4 u0 = h16[(size_t)csrSrc[e] * 8 + c];
                add8(a, u0);
            }
            unsigned d[4];
#pragma unroll
            for (int p = 0; p < 4; ++p)
                d[p] = (unsigned)f2b(a[2 * p]) | ((unsigned)f2b(a[2 * p + 1]) << 16);
            *(uint4*)(smem + nl * 72 + c * 8) = make_uint4(d[0], d[1], d[2], d[3]);
        }
    }
    __syncthreads();

    // ---- Phase B: MFMA matvec (A from LDS for agg, global for self) ----
    int w = t >> 6;
    int l = t & 63;
    int quad = l >> 4;
    int lo = l & 15;

    f32x4 acc[2][4];
#pragma unroll
    for (int ot = 0; ot < 4; ++ot) {
        float bv = bl[ot * 16 + lo];
        f32x4 bvv = {bv, bv, bv, bv};
        acc[0][ot] = bvv;
        acc[1][ot] = bvv;
    }

#pragma unroll
    for (int s = 0; s < 4; ++s) {
        bf16x8 A[2];
#pragma unroll
        for (int mt = 0; mt < 2; ++mt) {
            if (s < 2) {
                int nl = w * 32 + mt * 16 + lo;
                A[mt] = *(const bf16x8*)(smem + nl * 72 + s * 32 + quad * 8);
            } else {
                size_t node = (size_t)node0b + w * 32 + mt * 16 + lo;
                A[mt] = *(const bf16x8*)(hb + node * 64 + (s & 1) * 32 + quad * 8);
            }
        }
#pragma unroll
        for (int ot = 0; ot < 4; ++ot) {
            bf16x8 B = *(const bf16x8*)(wbuf + (((s * 4 + ot) * 64) + l) * 8);
#pragma unroll
            for (int mt = 0; mt < 2; ++mt)
                acc[mt][ot] = __builtin_amdgcn_mfma_f32_16x16x32_bf16(
                    A[mt], B, acc[mt][ot], 0, 0, 0);
        }
    }
    __syncthreads();               // all aggL reads done; smem becomes outT

    // ---- Epilogue: tanh + transpose via LDS, two 64-row halves ----
    float* outT = (float*)smem;
    int whalf = w >> 1;            // which half this wave's rows belong to
    int wrow = (w & 1) * 32;       // row base within the half

#pragma unroll
    for (int half = 0; half < 2; ++half) {
        if (whalf == half) {
#pragma unroll
            for (int mt = 0; mt < 2; ++mt) {
#pragma unroll
                for (int ot = 0; ot < 4; ++ot) {
                    f32x4 v = acc[mt][ot];
                    if (flags & 1) {
                        v[0] = tanhf(v[0]); v[1] = tanhf(v[1]);
                        v[2] = tanhf(v[2]); v[3] = tanhf(v[3]);
                    }
                    int row = wrow + mt * 16 + quad * 4;
                    int col = ot * 16 + lo;
#pragma unroll
                    for (int r = 0; r < 4; ++r)
                        outT[(row + r) * 68 + col] = v[r];
                }
            }
        }
        __syncthreads();
        // cooperative store of this half's 64 rows: 4 lanes/row x 16 cols
        int hr = t >> 2;
        int node = node0b + half * 64 + hr;
        if (node < n) {
            const float* srcp = &outT[hr * 68 + (t & 3) * 16];
            if (flags & 2) {
                uint4* o8 = (uint4*)out;     // bf16 row = 8 uint4
#pragma unroll
                for (int q = 0; q < 2; ++q) {
                    unsigned dd[4];
#pragma unroll
                    for (int p = 0; p < 4; ++p) {
                        float va = srcp[q * 8 + 2 * p];
                        float vb = srcp[q * 8 + 2 * p + 1];
                        dd[p] = (unsigned)f2b(va) | ((unsigned)f2b(vb) << 16);
                    }
                    o8[(size_t)node * 8 + (t & 3) * 2 + q] =
                        make_uint4(dd[0], dd[1], dd[2], dd[3]);
                }
            } else {
                float4* o16 = (float4*)out;  // fp32 row = 16 float4
#pragma unroll
                for (int q = 0; q < 4; ++q) {
                    float4 v = *(const float4*)(srcp + q * 4);
                    o16[(size_t)node * 16 + (t & 3) * 4 + q] = v;
                }
            }
        }
        if (half == 0) __syncthreads();      // protect outT before half-1 writes
    }
}

// ---------------------------------------------------------------------------
// Launch
// ---------------------------------------------------------------------------
extern "C" void kernel_launch(void* const* d_in, const int* in_sizes, int n_in,
                              void* d_out, int out_size, void* d_ws, size_t ws_size,
                              hipStream_t stream) {
    const float* x      = (const float*)d_in[0];
    const int*   edges  = (const int*)d_in[1];
    const float* Wl_in  = (const float*)d_in[2];
    const float* bl_in  = (const float*)d_in[3];
    const float* Wr_in  = (const float*)d_in[4];
    const float* Wl_med = (const float*)d_in[5];
    const float* bl_med = (const float*)d_in[6];
    const float* Wr_med = (const float*)d_in[7];
    const float* Wl_out = (const float*)d_in[8];
    const float* bl_out = (const float*)d_in[9];
    const float* Wr_out = (const float*)d_in[10];

    const int N = in_sizes[0] / F;
    const int E = in_sizes[1] / 2;
    const int* src = edges;
    const int* dst = edges + E;

    const int nf  = (N + 127) >> 7;              // fine buckets (782)
    const int NB1 = (E + TILE1 - 1) / TILE1;     // bucketing tiles (147)
    const int NR  = nf * 128;                    // padded node count
    const int scanLen = nf * NB1;
    const int nbScan = (scanLen + SCAN_BLK - 1) / SCAN_BLK;

    // Workspace layout (16B-aligned chunks)
    ushort*  wbuf      = (ushort*)d_ws;                        // 3*8192 bf16
    ushort*  xb        = wbuf + 3 * 8192;                      // NR*F bf16
    ushort*  hAb       = xb + (size_t)NR * F;                  // NR*F bf16
    ushort*  hBb       = hAb + (size_t)NR * F;                 // NR*F bf16
    int*     rowStart  = (int*)(hBb + (size_t)NR * F);         // NR+2
    int*     blockSums = rowStart + NR + 2;                    // nbScan (<=1024)
    int*     binMat    = blockSums + SCAN_BLK;                 // nf*NB1
    unsigned* stage2   = (unsigned*)(binMat + scanLen);        // E
    int*     csrSrc    = (int*)(stage2 + E);                   // E

    const int prep_blocks = 12 + (N * F / 4 + 255) / 256;

    // Prep (weight B-frags + x->bf16)
    prep_kernel<<<prep_blocks, 256, 0, stream>>>(Wl_in, Wr_in, Wl_med, Wr_med,
                                                 Wl_out, Wr_out, wbuf, x, xb, N * F);

    // Single-level fine bucketing -> csrSrc + rowStart
    hist_kernel<<<NB1, 256, 0, stream>>>(dst, binMat, E, NB1, nf);
    scan_blocks_kernel<<<nbScan, SCAN_BLK, 0, stream>>>(binMat, blockSums, scanLen);
    scan_sums_kernel<<<1, SCAN_BLK, 0, stream>>>(blockSums, nbScan);
    scan_add_kernel<<<(scanLen + 255) / 256, 256, 0, stream>>>(binMat, blockSums, scanLen);
    scatter_kernel<<<NB1, 256, 0, stream>>>(src, dst, binMat, stage2, E, NB1, nf);
    phase2_kernel<<<nf, 256, 0, stream>>>(stage2, binMat, csrSrc, rowStart, E, NB1, nf);

    // Fused layers: gather + MFMA matvec in one kernel per layer
    fused_layer<<<nf, 256, 0, stream>>>(xb,  rowStart, csrSrc, wbuf,         bl_in,  hAb,   N, 3);
    fused_layer<<<nf, 256, 0, stream>>>(hAb, rowStart, csrSrc, wbuf + 8192,  bl_med, hBb,   N, 3);
    fused_layer<<<nf, 256, 0, stream>>>(hBb, rowStart, csrSrc, wbuf + 8192,  bl_med, hAb,   N, 3);
    fused_layer<<<nf, 256, 0, stream>>>(hAb, rowStart, csrSrc, wbuf + 16384, bl_out, d_out, N, 0);
}